// Round 10
// baseline (258.322 us; speedup 1.0000x reference)
//
#include <hip/hip_runtime.h>
#include <hip/hip_bf16.h>

#define SEQ 2048
#define DM  1024
#define NH  4
#define HD  256

typedef __attribute__((ext_vector_type(4))) float f32x4;
typedef __attribute__((ext_vector_type(16))) float f32x16;
typedef __attribute__((ext_vector_type(8))) short bf16x8;

__device__ __forceinline__ void gload16(const void* g, void* l) {
  __builtin_amdgcn_global_load_lds(
      (__attribute__((address_space(1))) void*)(unsigned long long)(g),
      (__attribute__((address_space(3))) void*)(l), 16, 0, 0);
}

__device__ __forceinline__ bf16x8 ldg8(const __hip_bfloat16* p) {
  return *reinterpret_cast<const bf16x8*>(p);
}

__device__ __forceinline__ unsigned pack2(float a, float b) {
  __hip_bfloat162 t = __float22bfloat162_rn(make_float2(a, b));
  return *reinterpret_cast<unsigned*>(&t);  // short0=a, short1=b
}

__device__ __forceinline__ short bfbits(float x) {
  __hip_bfloat16 h = __float2bfloat16(x);
  return *reinterpret_cast<short*>(&h);
}

// ---------------- fp32 -> bf16 (x, qkv_w, wo_w fused: 3 launches -> 1) ----------------
__global__ __launch_bounds__(256) void cvt3(const float* __restrict__ x,
                                            const float* __restrict__ qw,
                                            const float* __restrict__ ww,
                                            __hip_bfloat16* __restrict__ xo,
                                            __hip_bfloat16* __restrict__ qo,
                                            __hip_bfloat16* __restrict__ wo) {
  int i = blockIdx.x * 256 + threadIdx.x;  // grid covers exactly 3145728 float4s
  const float* src;
  __hip_bfloat16* dst;
  int j;
  if (i < 2097152) {
    src = x; dst = xo; j = i;
  } else if (i < 2883584) {
    src = qw; dst = qo; j = i - 2097152;
  } else {
    src = ww; dst = wo; j = i - 2883584;
  }
  float4 v = reinterpret_cast<const float4*>(src)[j];
  __hip_bfloat162* o2 = reinterpret_cast<__hip_bfloat162*>(dst);
  o2[j * 2 + 0] = __float22bfloat162_rn(make_float2(v.x, v.y));
  o2[j * 2 + 1] = __float22bfloat162_rn(make_float2(v.z, v.w));
}

// ---------------- GEMM: C[m,n] = sum_k A[m,k]*B[n,k] (+bias, +resid) ----------------
// v3 (rounds 8-9, passed): counted-vmcnt 3-buffer ring + V-transpose fused epilogue. FROZEN.
template <int EPI>
__global__ __launch_bounds__(256, 3) void gemm_bt(
    const __hip_bfloat16* __restrict__ A, const __hip_bfloat16* __restrict__ Bw,
    const float* __restrict__ bias, const float* __restrict__ resid,
    __hip_bfloat16* __restrict__ Cb, float* __restrict__ Cf,
    __hip_bfloat16* __restrict__ vtr, int M, int N, int K) {
  __shared__ __hip_bfloat16 lA[3][128 * 32];  // 3 x 8 KB
  __shared__ __hip_bfloat16 lB[3][128 * 32];  // 3 x 8 KB   (48 KB -> 3 blocks/CU)
  const int t = threadIdx.x;
  const int w = t >> 6, l = t & 63;
  const int lg = l >> 4, li = l & 15;
  const int m0 = blockIdx.y * 128, n0 = blockIdx.x * 128;
  const int wm = (w >> 1) * 64, wn = (w & 1) * 64;
  // staging: thread covers rows (t>>2) and 64+(t>>2); pre-swizzled data chunk (same both rows)
  const int ca = (((t & 3) ^ ((t >> 3) & 3))) * 8;
  const __hip_bfloat16* gA0 = A + (size_t)(m0 + (t >> 2)) * K + ca;
  const __hip_bfloat16* gA1 = A + (size_t)(m0 + 64 + (t >> 2)) * K + ca;
  const __hip_bfloat16* gB0 = Bw + (size_t)(n0 + (t >> 2)) * K + ca;
  const __hip_bfloat16* gB1 = Bw + (size_t)(n0 + 64 + (t >> 2)) * K + ca;
  const int loff = t * 8;  // LDS linear dest (wave-uniform base + lane*16B)

  auto STAGE = [&](int kt, int buf) {
    const int k0 = kt * 32;
    gload16(gA0 + k0, &lA[buf][loff]);
    gload16(gA1 + k0, &lA[buf][loff + 2048]);
    gload16(gB0 + k0, &lB[buf][loff]);
    gload16(gB1 + k0, &lB[buf][loff + 2048]);
  };

  f32x4 acc[4][4] = {};
  const int T = K >> 5;
  STAGE(0, 0);
  STAGE(1, 1);
  asm volatile("s_waitcnt vmcnt(4)" ::: "memory");
  __builtin_amdgcn_sched_barrier(0);
  __builtin_amdgcn_s_barrier();
  __builtin_amdgcn_sched_barrier(0);
  int cur = 0, nx2 = 2;
  for (int kt = 0; kt < T; ++kt) {
    if (kt + 2 < T) STAGE(kt + 2, nx2);
    bf16x8 af[4], bfr[4];
#pragma unroll
    for (int i = 0; i < 4; i++) {
      const int row = wm + i * 16 + li;
      af[i] = ldg8(&lA[cur][row * 32 + ((lg ^ ((row >> 1) & 3)) << 3)]);
    }
#pragma unroll
    for (int i = 0; i < 4; i++) {
      const int row = wn + i * 16 + li;
      bfr[i] = ldg8(&lB[cur][row * 32 + ((lg ^ ((row >> 1) & 3)) << 3)]);
    }
    asm volatile("s_waitcnt lgkmcnt(0)" ::: "memory");
    __builtin_amdgcn_sched_barrier(0);
#pragma unroll
    for (int mi = 0; mi < 4; mi++)
#pragma unroll
      for (int ni = 0; ni < 4; ni++)
        acc[mi][ni] = __builtin_amdgcn_mfma_f32_16x16x32_bf16(af[mi], bfr[ni], acc[mi][ni], 0, 0, 0);
    if (kt + 2 < T) {
      asm volatile("s_waitcnt vmcnt(4)" ::: "memory");
    } else {
      asm volatile("s_waitcnt vmcnt(0)" ::: "memory");
    }
    __builtin_amdgcn_sched_barrier(0);
    __builtin_amdgcn_s_barrier();
    __builtin_amdgcn_sched_barrier(0);
    cur = (cur == 2) ? 0 : cur + 1;
    nx2 = (nx2 == 2) ? 0 : nx2 + 1;
  }
#pragma unroll
  for (int ni = 0; ni < 4; ni++) {
    const int col = n0 + wn + ni * 16 + li;
    const float bv = bias[col];
    if (EPI == 0 && col >= 2048) {
      // V projection -> vt[(b*4+h)*256+d][s], fused transpose
      const int hh = (col - 2048) >> 8;   // uniform per ni
      const int dd = (col - 2048) & 255;  // per-lane
      __hip_bfloat16* vcol =
          vtr + ((size_t)((m0 >> 11) * 4 + hh) * 256 + dd) * 2048 + (m0 & 2047);
#pragma unroll
      for (int mi = 0; mi < 4; mi++) {
        const int off = wm + mi * 16 + lg * 4;
#pragma unroll
        for (int r = 0; r < 4; r++)
          vcol[off + r] = __float2bfloat16(acc[mi][ni][r] + bv);
      }
    } else {
#pragma unroll
      for (int mi = 0; mi < 4; mi++) {
        const int rowb = m0 + wm + mi * 16 + lg * 4;
#pragma unroll
        for (int r = 0; r < 4; r++) {
          const size_t idx = (size_t)(rowb + r) * N + col;
          float v = acc[mi][ni][r] + bv;
          if (EPI) {
            Cf[idx] = v + resid[idx];
          } else {
            Cb[idx] = __float2bfloat16(v);
          }
        }
      }
    }
  }
}

// ---------------- flash attention v10: 256-thread blocks, full-kv per wave ----------------
// v9 post-mortem: 8 waves lockstepped by ONE __syncthreads per iter -- the two kv-groups are
// data-independent yet share a barrier domain, so the staging drain stalls the whole CU.
// v10: 4 waves x 32 q-rows per 256-thread block; each wave walks the FULL kv range (64 tiles
// of 32). LDS halves to 64 KB -> 2 independent blocks/CU (two barrier domains that phase-slip,
// round-0/7-proven mechanism). Same 8 waves/CU, same total wave-iters, same staging bytes.
// Deleted: kv-split groups, mlx, cross-group combine, xch LDS round-trip. Epilogue is a
// direct normalized store (lane owns its whole q-row; lsum identical across hi-halves via
// psum + shfl_xor(psum,32)): d = dt*32 + 8j + 4hi + s <-> oacc[dt][4j+s] -> 32 aligned
// short4 stores/lane. Inner loop byte-identical to v9 (3x passed).
__global__ __launch_bounds__(256, 2) void flash_attn(const __hip_bfloat16* __restrict__ qkv,
                                                     const __hip_bfloat16* __restrict__ vt,
                                                     __hip_bfloat16* __restrict__ attno) {
  __shared__ __hip_bfloat16 ldsK[2][32 * 256];  // [buf][kv 32][d 256]  32 KB
  __shared__ __hip_bfloat16 ldsV[2][256 * 32];  // [buf][d 256][kv 32]  32 KB
  const int tid = threadIdx.x, w = tid >> 6, l = tid & 63;
  const int l31 = l & 31, hi = l >> 5;
  const int bid = blockIdx.x;
  const int bh = (bid & 7) * 2 + ((bid >> 3) & 1);  // XCD-affine: 2 bh per XCD
  const int qt = bid >> 4;
  const int b = bh >> 2, h = bh & 3;
  const int qsub = qt * 128 + w * 32;
  // Q B-frags: bq[kst] = Q[q=l31][kst*16 + hi*8 + j]
  bf16x8 bq[16];
  {
    const __hip_bfloat16* Qp = qkv + (size_t)(b * SEQ + qsub + l31) * 3072 + h * HD + hi * 8;
#pragma unroll
    for (int kst = 0; kst < 16; kst++) bq[kst] = ldg8(Qp + kst * 16);
  }
  // K staging: round i (i<4) writes rows kv=i*8+(tid>>5); phys chunk tid&31 holds data ^(kv&7)
  const int kcd = (tid & 31) ^ ((tid >> 5) & 7);
  const __hip_bfloat16* Kg =
      qkv + (size_t)(b * SEQ + (tid >> 5)) * 3072 + 1024 + h * HD + kcd * 8;
  // V staging: round i (i<4) writes rows d=i*64+(tid>>2); phys chunk tid&3 holds data ^((d>>1)&3)
  const int vcd = (tid & 3) ^ ((tid >> 3) & 3);
  const __hip_bfloat16* Vg =
      vt + (size_t)bh * HD * SEQ + (size_t)(tid >> 2) * SEQ + vcd * 8;

  f32x16 oacc[8] = {};
  float m_run = -1e30f, lsum = 0.f;

  // prologue: stage tile 0 into buf 0
#pragma unroll
  for (int i = 0; i < 4; i++) gload16(Kg + (size_t)(i * 8) * 3072, &ldsK[0][i * 2048 + tid * 8]);
#pragma unroll
  for (int i = 0; i < 4; i++) gload16(Vg + (size_t)(i * 64) * SEQ, &ldsV[0][i * 2048 + tid * 8]);
  __syncthreads();

#pragma unroll 2
  for (int t = 0; t < 64; ++t) {
    const int cur = t & 1;
    // ---- issue next tile's loads first: latency hides under this tile's compute ----
    if (t + 1 < 64) {
      const int nk = (t + 1) * 32;
#pragma unroll
      for (int i = 0; i < 4; i++)
        gload16(Kg + (size_t)(nk + i * 8) * 3072, &ldsK[cur ^ 1][i * 2048 + tid * 8]);
#pragma unroll
      for (int i = 0; i < 4; i++)
        gload16(Vg + (size_t)(i * 64) * SEQ + nk, &ldsV[cur ^ 1][i * 2048 + tid * 8]);
    }
    const __hip_bfloat16* lK = &ldsK[cur][0];
    const __hip_bfloat16* lV = &ldsV[cur][0];
    // ---- S^T[kv32][q]: 16 MFMAs, 2 independent chains ----
    f32x16 sa = {}, sb = {};
    const int ksw = l31 & 7;
    __builtin_amdgcn_s_setprio(1);
#pragma unroll
    for (int kst = 0; kst < 8; kst++) {
      bf16x8 aka = ldg8(&lK[l31 * 256 + (((4 * kst + hi) ^ ksw) << 3)]);
      bf16x8 akb = ldg8(&lK[l31 * 256 + (((4 * kst + 2 + hi) ^ ksw) << 3)]);
      sa = __builtin_amdgcn_mfma_f32_32x32x16_bf16(aka, bq[2 * kst], sa, 0, 0, 0);
      sb = __builtin_amdgcn_mfma_f32_32x32x16_bf16(akb, bq[2 * kst + 1], sb, 0, 0, 0);
    }
    __builtin_amdgcn_s_setprio(0);
#pragma unroll
    for (int r = 0; r < 16; r++) sa[r] = (sa[r] + sb[r]) * 0.0625f;  // hd^-0.5
    // ---- in-register online softmax (lane owns q=l31; partner l^32 has other 16 rows) ----
    float rmax = sa[0];
#pragma unroll
    for (int r = 1; r < 16; r++) rmax = fmaxf(rmax, sa[r]);
    rmax = fmaxf(rmax, __shfl_xor(rmax, 32));
    if (rmax > m_run + 8.f) {  // defer-max THR=8
      const float alpha = __expf(m_run - rmax);
      m_run = rmax;
      lsum *= alpha;
#pragma unroll
      for (int dt = 0; dt < 8; dt++)
#pragma unroll
        for (int r = 0; r < 16; r++) oacc[dt][r] *= alpha;
    }
    float psum = 0.f;
#pragma unroll
    for (int r = 0; r < 16; r++) {
      sa[r] = __expf(sa[r] - m_run);  // bounded by e^8
      psum += sa[r];
    }
    lsum += psum + __shfl_xor(psum, 32);
    // ---- pack P^T into B-frags + PV (2 k-steps of 16 kv) ----
#pragma unroll
    for (int ks = 0; ks < 2; ks++) {
      const int rb = ks * 8;
      // own packs: a* = kv16 (4hi+0..3); b* = kv16 (8+4hi..11+4hi)
      unsigned a0 = pack2(sa[rb + 0], sa[rb + 1]);
      unsigned a1 = pack2(sa[rb + 2], sa[rb + 3]);
      unsigned b0 = pack2(sa[rb + 4], sa[rb + 5]);
      unsigned b1 = pack2(sa[rb + 6], sa[rb + 7]);
      // hi=0 sends b*, receives partner a* (kv16 4-7); hi=1 sends a*, receives b* (kv16 8-11)
      unsigned s0 = (unsigned)__shfl_xor((int)(hi ? a0 : b0), 32);
      unsigned s1 = (unsigned)__shfl_xor((int)(hi ? a1 : b1), 32);
      union { unsigned u[4]; bf16x8 v; } pw;
      pw.u[0] = hi ? s0 : a0;  // k = hi*8 + {0,1}
      pw.u[1] = hi ? s1 : a1;  // k = hi*8 + {2,3}
      pw.u[2] = hi ? b0 : s0;  // k = hi*8 + {4,5}
      pw.u[3] = hi ? b1 : s1;  // k = hi*8 + {6,7}
      // PV: O^T[d][q] += V^T[d][kv] * P^T[kv][q]; A-frag k=hi*8+j -> data chunk ks*2+hi
      __builtin_amdgcn_s_setprio(1);
#pragma unroll
      for (int dt = 0; dt < 8; dt++) {
        const int drow = dt * 32 + l31;
        bf16x8 av = ldg8(&lV[drow * 32 + (((ks * 2 + hi) ^ ((drow >> 1) & 3)) << 3)]);
        oacc[dt] = __builtin_amdgcn_mfma_f32_32x32x16_bf16(av, pw.v, oacc[dt], 0, 0, 0);
      }
      __builtin_amdgcn_s_setprio(0);
    }
    // one barrier per iter: drains in-flight next-tile loads AND guards buffer reuse
    __syncthreads();
  }
  // ---- epilogue: direct normalized store (no combine; lane owns full q-row) ----
  const float inv = 1.f / lsum;
  __hip_bfloat16* orow = attno + (size_t)(b * SEQ + qsub + l31) * DM + h * HD + 4 * hi;
#pragma unroll
  for (int dt = 0; dt < 8; dt++)
#pragma unroll
    for (int j = 0; j < 4; j++) {
      short4 sv;
      sv.x = bfbits(oacc[dt][4 * j + 0] * inv);
      sv.y = bfbits(oacc[dt][4 * j + 1] * inv);
      sv.z = bfbits(oacc[dt][4 * j + 2] * inv);
      sv.w = bfbits(oacc[dt][4 * j + 3] * inv);
      *reinterpret_cast<short4*>(reinterpret_cast<short*>(orow + dt * 32 + 8 * j)) = sv;
    }
}

// ---------------- LayerNorm: 1 wave per 1024-row ----------------
__global__ __launch_bounds__(256) void layernorm_k(const float* __restrict__ y,
                                                   const float* __restrict__ gamma,
                                                   const float* __restrict__ beta,
                                                   float* __restrict__ out) {
  const int w = threadIdx.x >> 6, l = threadIdx.x & 63;
  const size_t row = (size_t)blockIdx.x * 4 + w;
  const float4* yp = reinterpret_cast<const float4*>(y + row * DM);
  float4 v[4];
  float s = 0.f, s2 = 0.f;
#pragma unroll
  for (int i = 0; i < 4; i++) {
    v[i] = yp[i * 64 + l];
    s += v[i].x + v[i].y + v[i].z + v[i].w;
    s2 += v[i].x * v[i].x + v[i].y * v[i].y + v[i].z * v[i].z + v[i].w * v[i].w;
  }
#pragma unroll
  for (int off = 1; off < 64; off <<= 1) {
    s += __shfl_xor(s, off);
    s2 += __shfl_xor(s2, off);
  }
  const float mu = s * (1.f / 1024.f);
  const float rs = rsqrtf(s2 * (1.f / 1024.f) - mu * mu + 1e-5f);
  const float4* gp = reinterpret_cast<const float4*>(gamma);
  const float4* bp = reinterpret_cast<const float4*>(beta);
  float4* op = reinterpret_cast<float4*>(out + row * DM);
#pragma unroll
  for (int i = 0; i < 4; i++) {
    float4 g = gp[i * 64 + l], bb = bp[i * 64 + l];
    float4 o;
    o.x = (v[i].x - mu) * rs * g.x + bb.x;
    o.y = (v[i].y - mu) * rs * g.y + bb.y;
    o.z = (v[i].z - mu) * rs * g.z + bb.z;
    o.w = (v[i].w - mu) * rs * g.w + bb.w;
    op[i * 64 + l] = o;
  }
}

extern "C" void kernel_launch(void* const* d_in, const int* in_sizes, int n_in,
                              void* d_out, int out_size, void* d_ws, size_t ws_size,
                              hipStream_t stream) {
  const float* x     = (const float*)d_in[0];
  const float* qkv_w = (const float*)d_in[1];
  const float* qkv_b = (const float*)d_in[2];
  const float* wo_w  = (const float*)d_in[3];
  const float* wo_b  = (const float*)d_in[4];
  const float* gamma = (const float*)d_in[5];
  const float* beta  = (const float*)d_in[6];
  float* out = (float*)d_out;
  char* ws = (char*)d_ws;
  // v0 workspace layout (passed 9x): strictly sequential lifetimes, no overlap while live.
  __hip_bfloat16* xbf   = (__hip_bfloat16*)(ws);             // dead after gemm<0>
  __hip_bfloat16* qkvwb = (__hip_bfloat16*)(ws + 16777216);  // dead after gemm<0>
  __hip_bfloat16* wowb  = (__hip_bfloat16*)(ws + 23068672);  // live until gemm<1>
  __hip_bfloat16* qkv   = (__hip_bfloat16*)(ws + 25165824);  // dead after flash
  float*          yb    = (float*)(ws + 25165824);           // gemm<1> out (aliases dead qkv)
  __hip_bfloat16* vt    = (__hip_bfloat16*)(ws + 75497472);  // dead after flash
  __hip_bfloat16* attno = xbf;                               // flash out (aliases dead xbf)

  cvt3<<<12288, 256, 0, stream>>>(x, qkv_w, wo_w, xbf, qkvwb, wowb);
  gemm_bt<0><<<dim3(24, 64), 256, 0, stream>>>(xbf, qkvwb, qkv_b, nullptr, qkv, nullptr,
                                               vt, 8192, 3072, 1024);
  flash_attn<<<256, 256, 0, stream>>>(qkv, vt, attno);
  gemm_bt<1><<<dim3(8, 64), 256, 0, stream>>>(attno, wowb, wo_b, x, nullptr, yb,
                                              nullptr, 8192, 1024, 1024);
  layernorm_k<<<2048, 256, 0, stream>>>(yb, gamma, beta, out);
}

// Round 11
// 232.395 us; speedup vs baseline: 1.1116x; 1.1116x over previous
//
#include <hip/hip_runtime.h>
#include <hip/hip_bf16.h>

#define SEQ 2048
#define DM  1024
#define NH  4
#define HD  256

typedef __attribute__((ext_vector_type(4))) float f32x4;
typedef __attribute__((ext_vector_type(16))) float f32x16;
typedef __attribute__((ext_vector_type(8))) short bf16x8;

__device__ __forceinline__ void gload16(const void* g, void* l) {
  __builtin_amdgcn_global_load_lds(
      (__attribute__((address_space(1))) void*)(unsigned long long)(g),
      (__attribute__((address_space(3))) void*)(l), 16, 0, 0);
}

__device__ __forceinline__ bf16x8 ldg8(const __hip_bfloat16* p) {
  return *reinterpret_cast<const bf16x8*>(p);
}

__device__ __forceinline__ unsigned pack2(float a, float b) {
  __hip_bfloat162 t = __float22bfloat162_rn(make_float2(a, b));
  return *reinterpret_cast<unsigned*>(&t);  // short0=a, short1=b
}

__device__ __forceinline__ short bfbits(float x) {
  __hip_bfloat16 h = __float2bfloat16(x);
  return *reinterpret_cast<short*>(&h);
}

__device__ __forceinline__ float b2f(short s) {
  union { unsigned u; float f; } c;
  c.u = ((unsigned)(unsigned short)s) << 16;
  return c.f;
}

// ---------------- fp32 -> bf16 (x, qkv_w, wo_w fused: 3 launches -> 1) ----------------
__global__ __launch_bounds__(256) void cvt3(const float* __restrict__ x,
                                            const float* __restrict__ qw,
                                            const float* __restrict__ ww,
                                            __hip_bfloat16* __restrict__ xo,
                                            __hip_bfloat16* __restrict__ qo,
                                            __hip_bfloat16* __restrict__ wo) {
  int i = blockIdx.x * 256 + threadIdx.x;  // grid covers exactly 3145728 float4s
  const float* src;
  __hip_bfloat16* dst;
  int j;
  if (i < 2097152) {
    src = x; dst = xo; j = i;
  } else if (i < 2883584) {
    src = qw; dst = qo; j = i - 2097152;
  } else {
    src = ww; dst = wo; j = i - 2883584;
  }
  float4 v = reinterpret_cast<const float4*>(src)[j];
  __hip_bfloat162* o2 = reinterpret_cast<__hip_bfloat162*>(dst);
  o2[j * 2 + 0] = __float22bfloat162_rn(make_float2(v.x, v.y));
  o2[j * 2 + 1] = __float22bfloat162_rn(make_float2(v.z, v.w));
}

// ---------------- GEMM: C[m,n] = sum_k A[m,k]*B[n,k] (+bias, +resid) ----------------
// v3 (rounds 8-10, passed): counted-vmcnt 3-buffer ring + V-transpose fused epilogue.
// v4 delta: EPI=1 writes y in BF16 (Cb) -- halves y write traffic; LN consumes bf16.
template <int EPI>
__global__ __launch_bounds__(256, 3) void gemm_bt(
    const __hip_bfloat16* __restrict__ A, const __hip_bfloat16* __restrict__ Bw,
    const float* __restrict__ bias, const float* __restrict__ resid,
    __hip_bfloat16* __restrict__ Cb,
    __hip_bfloat16* __restrict__ vtr, int M, int N, int K) {
  __shared__ __hip_bfloat16 lA[3][128 * 32];  // 3 x 8 KB
  __shared__ __hip_bfloat16 lB[3][128 * 32];  // 3 x 8 KB   (48 KB -> 3 blocks/CU)
  const int t = threadIdx.x;
  const int w = t >> 6, l = t & 63;
  const int lg = l >> 4, li = l & 15;
  const int m0 = blockIdx.y * 128, n0 = blockIdx.x * 128;
  const int wm = (w >> 1) * 64, wn = (w & 1) * 64;
  // staging: thread covers rows (t>>2) and 64+(t>>2); pre-swizzled data chunk (same both rows)
  const int ca = (((t & 3) ^ ((t >> 3) & 3))) * 8;
  const __hip_bfloat16* gA0 = A + (size_t)(m0 + (t >> 2)) * K + ca;
  const __hip_bfloat16* gA1 = A + (size_t)(m0 + 64 + (t >> 2)) * K + ca;
  const __hip_bfloat16* gB0 = Bw + (size_t)(n0 + (t >> 2)) * K + ca;
  const __hip_bfloat16* gB1 = Bw + (size_t)(n0 + 64 + (t >> 2)) * K + ca;
  const int loff = t * 8;  // LDS linear dest (wave-uniform base + lane*16B)

  auto STAGE = [&](int kt, int buf) {
    const int k0 = kt * 32;
    gload16(gA0 + k0, &lA[buf][loff]);
    gload16(gA1 + k0, &lA[buf][loff + 2048]);
    gload16(gB0 + k0, &lB[buf][loff]);
    gload16(gB1 + k0, &lB[buf][loff + 2048]);
  };

  f32x4 acc[4][4] = {};
  const int T = K >> 5;
  STAGE(0, 0);
  STAGE(1, 1);
  asm volatile("s_waitcnt vmcnt(4)" ::: "memory");
  __builtin_amdgcn_sched_barrier(0);
  __builtin_amdgcn_s_barrier();
  __builtin_amdgcn_sched_barrier(0);
  int cur = 0, nx2 = 2;
  for (int kt = 0; kt < T; ++kt) {
    if (kt + 2 < T) STAGE(kt + 2, nx2);
    bf16x8 af[4], bfr[4];
#pragma unroll
    for (int i = 0; i < 4; i++) {
      const int row = wm + i * 16 + li;
      af[i] = ldg8(&lA[cur][row * 32 + ((lg ^ ((row >> 1) & 3)) << 3)]);
    }
#pragma unroll
    for (int i = 0; i < 4; i++) {
      const int row = wn + i * 16 + li;
      bfr[i] = ldg8(&lB[cur][row * 32 + ((lg ^ ((row >> 1) & 3)) << 3)]);
    }
    asm volatile("s_waitcnt lgkmcnt(0)" ::: "memory");
    __builtin_amdgcn_sched_barrier(0);
#pragma unroll
    for (int mi = 0; mi < 4; mi++)
#pragma unroll
      for (int ni = 0; ni < 4; ni++)
        acc[mi][ni] = __builtin_amdgcn_mfma_f32_16x16x32_bf16(af[mi], bfr[ni], acc[mi][ni], 0, 0, 0);
    if (kt + 2 < T) {
      asm volatile("s_waitcnt vmcnt(4)" ::: "memory");
    } else {
      asm volatile("s_waitcnt vmcnt(0)" ::: "memory");
    }
    __builtin_amdgcn_sched_barrier(0);
    __builtin_amdgcn_s_barrier();
    __builtin_amdgcn_sched_barrier(0);
    cur = (cur == 2) ? 0 : cur + 1;
    nx2 = (nx2 == 2) ? 0 : nx2 + 1;
  }
#pragma unroll
  for (int ni = 0; ni < 4; ni++) {
    const int col = n0 + wn + ni * 16 + li;
    const float bv = bias[col];
    if (EPI == 0 && col >= 2048) {
      // V projection -> vt[(b*4+h)*256+d][s], fused transpose
      const int hh = (col - 2048) >> 8;   // uniform per ni
      const int dd = (col - 2048) & 255;  // per-lane
      __hip_bfloat16* vcol =
          vtr + ((size_t)((m0 >> 11) * 4 + hh) * 256 + dd) * 2048 + (m0 & 2047);
#pragma unroll
      for (int mi = 0; mi < 4; mi++) {
        const int off = wm + mi * 16 + lg * 4;
#pragma unroll
        for (int r = 0; r < 4; r++)
          vcol[off + r] = __float2bfloat16(acc[mi][ni][r] + bv);
      }
    } else {
#pragma unroll
      for (int mi = 0; mi < 4; mi++) {
        const int rowb = m0 + wm + mi * 16 + lg * 4;
#pragma unroll
        for (int r = 0; r < 4; r++) {
          const size_t idx = (size_t)(rowb + r) * N + col;
          float v = acc[mi][ni][r] + bv;
          if (EPI) {
            Cb[idx] = __float2bfloat16(v + resid[idx]);  // y in bf16
          } else {
            Cb[idx] = __float2bfloat16(v);
          }
        }
      }
    }
  }
}

// ---------------- flash attention v9 (VERBATIM round-7/8/9 kernel, 117.4us, 3x passed) ------
__global__ __launch_bounds__(512, 2) void flash_attn(const __hip_bfloat16* __restrict__ qkv,
                                                     const __hip_bfloat16* __restrict__ vt,
                                                     __hip_bfloat16* __restrict__ attno) {
  __shared__ __hip_bfloat16 ldsK[2][2][32 * 256];  // [group][buf][kv 32][d 256]  64 KB
  __shared__ __hip_bfloat16 ldsV[2][2][256 * 32];  // [group][buf][d 256][kv 32]  64 KB
  __shared__ float mlx[8][2][32];                  // [wave][m,l][q]              2 KB
  const int tid = threadIdx.x, w = tid >> 6, l = tid & 63;
  const int l31 = l & 31, hi = l >> 5;
  const int g = w >> 2, gt = tid & 255;
  const int bid = blockIdx.x;
  const int bh = (bid & 7) * 2 + ((bid >> 3) & 1);  // XCD-affine: 2 bh per XCD
  const int qt = bid >> 4;
  const int b = bh >> 2, h = bh & 3;
  const int qsub = qt * 128 + (w & 3) * 32;
  const int kvbase = g * 1024;
  // Q B-frags: bq[kst] = Q[q=l31][kst*16 + hi*8 + j]
  bf16x8 bq[16];
  {
    const __hip_bfloat16* Qp = qkv + (size_t)(b * SEQ + qsub + l31) * 3072 + h * HD + hi * 8;
#pragma unroll
    for (int kst = 0; kst < 16; kst++) bq[kst] = ldg8(Qp + kst * 16);
  }
  // K staging: round i (i<4) writes rows kv=i*8+(gt>>5); phys chunk gt&31 holds data ^(kv&7)
  const int kcd = (gt & 31) ^ ((gt >> 5) & 7);
  const __hip_bfloat16* Kg =
      qkv + (size_t)(b * SEQ + kvbase + (gt >> 5)) * 3072 + 1024 + h * HD + kcd * 8;
  // V staging: round i (i<4) writes rows d=i*64+(gt>>2); phys chunk gt&3 holds data ^((d>>1)&3)
  const int vcd = (gt & 3) ^ ((gt >> 3) & 3);
  const __hip_bfloat16* Vg =
      vt + (size_t)bh * HD * SEQ + (size_t)(gt >> 2) * SEQ + kvbase + vcd * 8;
  __hip_bfloat16* lKb[2] = {&ldsK[g][0][0], &ldsK[g][1][0]};
  __hip_bfloat16* lVb[2] = {&ldsV[g][0][0], &ldsV[g][1][0]};

  f32x16 oacc[8] = {};
  float m_run = -1e30f, lsum = 0.f;

  // prologue: stage tile 0 into buf 0
#pragma unroll
  for (int i = 0; i < 4; i++) gload16(Kg + (size_t)(i * 8) * 3072, lKb[0] + i * 2048 + gt * 8);
#pragma unroll
  for (int i = 0; i < 4; i++) gload16(Vg + (size_t)(i * 64) * SEQ, lVb[0] + i * 2048 + gt * 8);
  __syncthreads();

#pragma unroll 2
  for (int t = 0; t < 32; ++t) {
    const int cur = t & 1;
    // ---- issue next tile's loads first: latency hides under this tile's compute ----
    if (t + 1 < 32) {
      const int nk = (t + 1) * 32;
#pragma unroll
      for (int i = 0; i < 4; i++)
        gload16(Kg + (size_t)(nk + i * 8) * 3072, lKb[cur ^ 1] + i * 2048 + gt * 8);
#pragma unroll
      for (int i = 0; i < 4; i++)
        gload16(Vg + (size_t)(i * 64) * SEQ + nk, lVb[cur ^ 1] + i * 2048 + gt * 8);
    }
    const __hip_bfloat16* lK = lKb[cur];
    const __hip_bfloat16* lV = lVb[cur];
    // ---- S^T[kv32][q]: 16 MFMAs, 2 independent chains ----
    f32x16 sa = {}, sb = {};
    const int ksw = l31 & 7;
    __builtin_amdgcn_s_setprio(1);
#pragma unroll
    for (int kst = 0; kst < 8; kst++) {
      bf16x8 aka = ldg8(&lK[l31 * 256 + (((4 * kst + hi) ^ ksw) << 3)]);
      bf16x8 akb = ldg8(&lK[l31 * 256 + (((4 * kst + 2 + hi) ^ ksw) << 3)]);
      sa = __builtin_amdgcn_mfma_f32_32x32x16_bf16(aka, bq[2 * kst], sa, 0, 0, 0);
      sb = __builtin_amdgcn_mfma_f32_32x32x16_bf16(akb, bq[2 * kst + 1], sb, 0, 0, 0);
    }
    __builtin_amdgcn_s_setprio(0);
#pragma unroll
    for (int r = 0; r < 16; r++) sa[r] = (sa[r] + sb[r]) * 0.0625f;  // hd^-0.5
    // ---- in-register online softmax (lane owns q=l31; partner l^32 has other 16 rows) ----
    float rmax = sa[0];
#pragma unroll
    for (int r = 1; r < 16; r++) rmax = fmaxf(rmax, sa[r]);
    rmax = fmaxf(rmax, __shfl_xor(rmax, 32));
    if (rmax > m_run + 8.f) {  // defer-max THR=8
      const float alpha = __expf(m_run - rmax);
      m_run = rmax;
      lsum *= alpha;
#pragma unroll
      for (int dt = 0; dt < 8; dt++)
#pragma unroll
        for (int r = 0; r < 16; r++) oacc[dt][r] *= alpha;
    }
    float psum = 0.f;
#pragma unroll
    for (int r = 0; r < 16; r++) {
      sa[r] = __expf(sa[r] - m_run);  // bounded by e^8
      psum += sa[r];
    }
    lsum += psum + __shfl_xor(psum, 32);
    // ---- pack P^T into B-frags + PV (2 k-steps of 16 kv) ----
#pragma unroll
    for (int ks = 0; ks < 2; ks++) {
      const int rb = ks * 8;
      // own packs: a* = kv16 (4hi+0..3); b* = kv16 (8+4hi..11+4hi)
      unsigned a0 = pack2(sa[rb + 0], sa[rb + 1]);
      unsigned a1 = pack2(sa[rb + 2], sa[rb + 3]);
      unsigned b0 = pack2(sa[rb + 4], sa[rb + 5]);
      unsigned b1 = pack2(sa[rb + 6], sa[rb + 7]);
      // hi=0 sends b*, receives partner a* (kv16 4-7); hi=1 sends a*, receives b* (kv16 8-11)
      unsigned s0 = (unsigned)__shfl_xor((int)(hi ? a0 : b0), 32);
      unsigned s1 = (unsigned)__shfl_xor((int)(hi ? a1 : b1), 32);
      union { unsigned u[4]; bf16x8 v; } pw;
      pw.u[0] = hi ? s0 : a0;  // k = hi*8 + {0,1}
      pw.u[1] = hi ? s1 : a1;  // k = hi*8 + {2,3}
      pw.u[2] = hi ? b0 : s0;  // k = hi*8 + {4,5}
      pw.u[3] = hi ? b1 : s1;  // k = hi*8 + {6,7}
      // PV: O^T[d][q] += V^T[d][kv] * P^T[kv][q]; A-frag k=hi*8+j -> data chunk ks*2+hi
      __builtin_amdgcn_s_setprio(1);
#pragma unroll
      for (int dt = 0; dt < 8; dt++) {
        const int drow = dt * 32 + l31;
        bf16x8 av = ldg8(&lV[drow * 32 + (((ks * 2 + hi) ^ ((drow >> 1) & 3)) << 3)]);
        oacc[dt] = __builtin_amdgcn_mfma_f32_32x32x16_bf16(av, pw.v, oacc[dt], 0, 0, 0);
      }
      __builtin_amdgcn_s_setprio(0);
    }
    // one barrier per iter: drains in-flight next-tile loads AND guards buffer reuse
    __syncthreads();
  }
  // ---- cross-group flash-combine (through dead K/V LDS; no global partials) ----
  if (l < 32) {
    mlx[w][0][l] = m_run;
    mlx[w][1][l] = lsum;
  }
  __syncthreads();
  {
    const float m_o = mlx[w ^ 4][0][l31];
    const float l_o = mlx[w ^ 4][1][l31];
    const float mm = fmaxf(m_run, m_o);
    const float e_s = __expf(m_run - mm), e_o = __expf(m_o - mm);
    const float wgt = e_s / (e_s * lsum + e_o * l_o);
#pragma unroll
    for (int dt = 0; dt < 8; dt++)
#pragma unroll
      for (int r = 0; r < 16; r++) oacc[dt][r] *= wgt;
  }
  const int pair = w & 3;
  float* xch = pair < 2 ? reinterpret_cast<float*>(&ldsK[0][0][0]) + pair * 8192
                        : reinterpret_cast<float*>(&ldsV[0][0][0]) + (pair - 2) * 8192;
  // exchange layout: float[32 q][256 d], 16B d-chunk swizzled ^ (q&7)
  if (g == 0) {
#pragma unroll
    for (int dt = 0; dt < 8; dt++)
#pragma unroll
      for (int rq = 0; rq < 4; rq++) {
        const int dch = dt * 8 + 2 * rq + hi;
        f32x4 v;
#pragma unroll
        for (int i = 0; i < 4; i++) v[i] = oacc[dt][4 * rq + i];
        *reinterpret_cast<f32x4*>(&xch[l31 * 256 + ((dch ^ (l31 & 7)) << 2)]) = v;
      }
  }
  __syncthreads();
  if (g == 1) {
    const size_t rowb = (size_t)(b * SEQ + qsub + l31) * DM + h * HD;
#pragma unroll
    for (int dt = 0; dt < 8; dt++)
#pragma unroll
      for (int rq = 0; rq < 4; rq++) {
        const int dch = dt * 8 + 2 * rq + hi;
        f32x4 p = *reinterpret_cast<const f32x4*>(&xch[l31 * 256 + ((dch ^ (l31 & 7)) << 2)]);
        short4 sv;
        sv.x = bfbits(p[0] + oacc[dt][4 * rq + 0]);
        sv.y = bfbits(p[1] + oacc[dt][4 * rq + 1]);
        sv.z = bfbits(p[2] + oacc[dt][4 * rq + 2]);
        sv.w = bfbits(p[3] + oacc[dt][4 * rq + 3]);
        *reinterpret_cast<short4*>(
            reinterpret_cast<short*>(attno + rowb + dt * 32 + 8 * rq + 4 * hi)) = sv;
      }
  }
}

// ---------------- LayerNorm: 1 wave per 1024-row, BF16 input ----------------
// y in bf16 (written by gemm1): per-lane 16 contiguous elems (2x bf16x8, 32B/lane --
// coalesced 2KB/row). f32 math internally; f32 output.
__global__ __launch_bounds__(256) void layernorm_k(const __hip_bfloat16* __restrict__ y,
                                                   const float* __restrict__ gamma,
                                                   const float* __restrict__ beta,
                                                   float* __restrict__ out) {
  const int w = threadIdx.x >> 6, l = threadIdx.x & 63;
  const size_t row = (size_t)blockIdx.x * 4 + w;
  const bf16x8* yp = reinterpret_cast<const bf16x8*>(y + row * DM);
  bf16x8 v0 = yp[l * 2], v1 = yp[l * 2 + 1];
  float f[16];
  float s = 0.f, s2 = 0.f;
#pragma unroll
  for (int j = 0; j < 8; j++) {
    f[j] = b2f(v0[j]);
    f[8 + j] = b2f(v1[j]);
  }
#pragma unroll
  for (int j = 0; j < 16; j++) {
    s += f[j];
    s2 += f[j] * f[j];
  }
#pragma unroll
  for (int off = 1; off < 64; off <<= 1) {
    s += __shfl_xor(s, off);
    s2 += __shfl_xor(s2, off);
  }
  const float mu = s * (1.f / 1024.f);
  const float rs = rsqrtf(s2 * (1.f / 1024.f) - mu * mu + 1e-5f);
  const float4* gp = reinterpret_cast<const float4*>(gamma);
  const float4* bp = reinterpret_cast<const float4*>(beta);
  float4* op = reinterpret_cast<float4*>(out + row * DM);
#pragma unroll
  for (int i = 0; i < 4; i++) {
    float4 g = gp[l * 4 + i], bb = bp[l * 4 + i];
    float4 o;
    o.x = (f[i * 4 + 0] - mu) * rs * g.x + bb.x;
    o.y = (f[i * 4 + 1] - mu) * rs * g.y + bb.y;
    o.z = (f[i * 4 + 2] - mu) * rs * g.z + bb.z;
    o.w = (f[i * 4 + 3] - mu) * rs * g.w + bb.w;
    op[l * 4 + i] = o;
  }
}

extern "C" void kernel_launch(void* const* d_in, const int* in_sizes, int n_in,
                              void* d_out, int out_size, void* d_ws, size_t ws_size,
                              hipStream_t stream) {
  const float* x     = (const float*)d_in[0];
  const float* qkv_w = (const float*)d_in[1];
  const float* qkv_b = (const float*)d_in[2];
  const float* wo_w  = (const float*)d_in[3];
  const float* wo_b  = (const float*)d_in[4];
  const float* gamma = (const float*)d_in[5];
  const float* beta  = (const float*)d_in[6];
  float* out = (float*)d_out;
  char* ws = (char*)d_ws;
  // v0 workspace layout (passed 10x): strictly sequential lifetimes, no overlap while live.
  __hip_bfloat16* xbf   = (__hip_bfloat16*)(ws);             // dead after gemm<0>
  __hip_bfloat16* qkvwb = (__hip_bfloat16*)(ws + 16777216);  // dead after gemm<0>
  __hip_bfloat16* wowb  = (__hip_bfloat16*)(ws + 23068672);  // live until gemm<1>
  __hip_bfloat16* qkv   = (__hip_bfloat16*)(ws + 25165824);  // dead after flash
  __hip_bfloat16* ybb   = (__hip_bfloat16*)(ws + 25165824);  // gemm<1> out bf16 (aliases dead qkv)
  __hip_bfloat16* vt    = (__hip_bfloat16*)(ws + 75497472);  // dead after flash
  __hip_bfloat16* attno = xbf;                               // flash out (aliases dead xbf)

  cvt3<<<12288, 256, 0, stream>>>(x, qkv_w, wo_w, xbf, qkvwb, wowb);
  gemm_bt<0><<<dim3(24, 64), 256, 0, stream>>>(xbf, qkvwb, qkv_b, nullptr, qkv,
                                               vt, 8192, 3072, 1024);
  flash_attn<<<256, 512, 0, stream>>>(qkv, vt, attno);
  gemm_bt<1><<<dim3(8, 64), 256, 0, stream>>>(attno, wowb, wo_b, x, ybb,
                                              nullptr, 8192, 1024, 1024);
  layernorm_k<<<2048, 256, 0, stream>>>(ybb, gamma, beta, out);
}

// Round 12
// 227.330 us; speedup vs baseline: 1.1363x; 1.0223x over previous
//
#include <hip/hip_runtime.h>
#include <hip/hip_bf16.h>

#define SEQ 2048
#define DM  1024
#define NH  4
#define HD  256

typedef __attribute__((ext_vector_type(4))) float f32x4;
typedef __attribute__((ext_vector_type(16))) float f32x16;
typedef __attribute__((ext_vector_type(8))) short bf16x8;

__device__ __forceinline__ void gload16(const void* g, void* l) {
  __builtin_amdgcn_global_load_lds(
      (__attribute__((address_space(1))) void*)(unsigned long long)(g),
      (__attribute__((address_space(3))) void*)(l), 16, 0, 0);
}

__device__ __forceinline__ bf16x8 ldg8(const __hip_bfloat16* p) {
  return *reinterpret_cast<const bf16x8*>(p);
}

__device__ __forceinline__ unsigned pack2(float a, float b) {
  __hip_bfloat162 t = __float22bfloat162_rn(make_float2(a, b));
  return *reinterpret_cast<unsigned*>(&t);  // short0=a, short1=b
}

__device__ __forceinline__ short bfbits(float x) {
  __hip_bfloat16 h = __float2bfloat16(x);
  return *reinterpret_cast<short*>(&h);
}

__device__ __forceinline__ float b2f(short s) {
  union { unsigned u; float f; } c;
  c.u = ((unsigned)(unsigned short)s) << 16;
  return c.f;
}

// ---------------- fp32 -> bf16 (x, qkv_w, wo_w fused: 3 launches -> 1) ----------------
__global__ __launch_bounds__(256) void cvt3(const float* __restrict__ x,
                                            const float* __restrict__ qw,
                                            const float* __restrict__ ww,
                                            __hip_bfloat16* __restrict__ xo,
                                            __hip_bfloat16* __restrict__ qo,
                                            __hip_bfloat16* __restrict__ wo) {
  int i = blockIdx.x * 256 + threadIdx.x;  // grid covers exactly 3145728 float4s
  const float* src;
  __hip_bfloat16* dst;
  int j;
  if (i < 2097152) {
    src = x; dst = xo; j = i;
  } else if (i < 2883584) {
    src = qw; dst = qo; j = i - 2097152;
  } else {
    src = ww; dst = wo; j = i - 2883584;
  }
  float4 v = reinterpret_cast<const float4*>(src)[j];
  __hip_bfloat162* o2 = reinterpret_cast<__hip_bfloat162*>(dst);
  o2[j * 2 + 0] = __float22bfloat162_rn(make_float2(v.x, v.y));
  o2[j * 2 + 1] = __float22bfloat162_rn(make_float2(v.z, v.w));
}

// ---------------- GEMM: C[m,n] = sum_k A[m,k]*B[n,k] (+bias, +resid) ----------------
// v4 (rounds 8-11, passed): counted-vmcnt 3-buffer ring + V-transpose fused epilogue;
// EPI=1 writes y in BF16. FROZEN.
template <int EPI>
__global__ __launch_bounds__(256, 3) void gemm_bt(
    const __hip_bfloat16* __restrict__ A, const __hip_bfloat16* __restrict__ Bw,
    const float* __restrict__ bias, const float* __restrict__ resid,
    __hip_bfloat16* __restrict__ Cb,
    __hip_bfloat16* __restrict__ vtr, int M, int N, int K) {
  __shared__ __hip_bfloat16 lA[3][128 * 32];  // 3 x 8 KB
  __shared__ __hip_bfloat16 lB[3][128 * 32];  // 3 x 8 KB   (48 KB -> 3 blocks/CU)
  const int t = threadIdx.x;
  const int w = t >> 6, l = t & 63;
  const int lg = l >> 4, li = l & 15;
  const int m0 = blockIdx.y * 128, n0 = blockIdx.x * 128;
  const int wm = (w >> 1) * 64, wn = (w & 1) * 64;
  // staging: thread covers rows (t>>2) and 64+(t>>2); pre-swizzled data chunk (same both rows)
  const int ca = (((t & 3) ^ ((t >> 3) & 3))) * 8;
  const __hip_bfloat16* gA0 = A + (size_t)(m0 + (t >> 2)) * K + ca;
  const __hip_bfloat16* gA1 = A + (size_t)(m0 + 64 + (t >> 2)) * K + ca;
  const __hip_bfloat16* gB0 = Bw + (size_t)(n0 + (t >> 2)) * K + ca;
  const __hip_bfloat16* gB1 = Bw + (size_t)(n0 + 64 + (t >> 2)) * K + ca;
  const int loff = t * 8;  // LDS linear dest (wave-uniform base + lane*16B)

  auto STAGE = [&](int kt, int buf) {
    const int k0 = kt * 32;
    gload16(gA0 + k0, &lA[buf][loff]);
    gload16(gA1 + k0, &lA[buf][loff + 2048]);
    gload16(gB0 + k0, &lB[buf][loff]);
    gload16(gB1 + k0, &lB[buf][loff + 2048]);
  };

  f32x4 acc[4][4] = {};
  const int T = K >> 5;
  STAGE(0, 0);
  STAGE(1, 1);
  asm volatile("s_waitcnt vmcnt(4)" ::: "memory");
  __builtin_amdgcn_sched_barrier(0);
  __builtin_amdgcn_s_barrier();
  __builtin_amdgcn_sched_barrier(0);
  int cur = 0, nx2 = 2;
  for (int kt = 0; kt < T; ++kt) {
    if (kt + 2 < T) STAGE(kt + 2, nx2);
    bf16x8 af[4], bfr[4];
#pragma unroll
    for (int i = 0; i < 4; i++) {
      const int row = wm + i * 16 + li;
      af[i] = ldg8(&lA[cur][row * 32 + ((lg ^ ((row >> 1) & 3)) << 3)]);
    }
#pragma unroll
    for (int i = 0; i < 4; i++) {
      const int row = wn + i * 16 + li;
      bfr[i] = ldg8(&lB[cur][row * 32 + ((lg ^ ((row >> 1) & 3)) << 3)]);
    }
    asm volatile("s_waitcnt lgkmcnt(0)" ::: "memory");
    __builtin_amdgcn_sched_barrier(0);
#pragma unroll
    for (int mi = 0; mi < 4; mi++)
#pragma unroll
      for (int ni = 0; ni < 4; ni++)
        acc[mi][ni] = __builtin_amdgcn_mfma_f32_16x16x32_bf16(af[mi], bfr[ni], acc[mi][ni], 0, 0, 0);
    if (kt + 2 < T) {
      asm volatile("s_waitcnt vmcnt(4)" ::: "memory");
    } else {
      asm volatile("s_waitcnt vmcnt(0)" ::: "memory");
    }
    __builtin_amdgcn_sched_barrier(0);
    __builtin_amdgcn_s_barrier();
    __builtin_amdgcn_sched_barrier(0);
    cur = (cur == 2) ? 0 : cur + 1;
    nx2 = (nx2 == 2) ? 0 : nx2 + 1;
  }
#pragma unroll
  for (int ni = 0; ni < 4; ni++) {
    const int col = n0 + wn + ni * 16 + li;
    const float bv = bias[col];
    if (EPI == 0 && col >= 2048) {
      // V projection -> vt[(b*4+h)*256+d][s], fused transpose
      const int hh = (col - 2048) >> 8;   // uniform per ni
      const int dd = (col - 2048) & 255;  // per-lane
      __hip_bfloat16* vcol =
          vtr + ((size_t)((m0 >> 11) * 4 + hh) * 256 + dd) * 2048 + (m0 & 2047);
#pragma unroll
      for (int mi = 0; mi < 4; mi++) {
        const int off = wm + mi * 16 + lg * 4;
#pragma unroll
        for (int r = 0; r < 4; r++)
          vcol[off + r] = __float2bfloat16(acc[mi][ni][r] + bv);
      }
    } else {
#pragma unroll
      for (int mi = 0; mi < 4; mi++) {
        const int rowb = m0 + wm + mi * 16 + lg * 4;
#pragma unroll
        for (int r = 0; r < 4; r++) {
          const size_t idx = (size_t)(rowb + r) * N + col;
          float v = acc[mi][ni][r] + bv;
          if (EPI) {
            Cb[idx] = __float2bfloat16(v + resid[idx]);  // y in bf16
          } else {
            Cb[idx] = __float2bfloat16(v);
          }
        }
      }
    }
  }
}

// ---------------- flash attention v9 (VERBATIM, 117.4us, 4x passed) ------
__global__ __launch_bounds__(512, 2) void flash_attn(const __hip_bfloat16* __restrict__ qkv,
                                                     const __hip_bfloat16* __restrict__ vt,
                                                     __hip_bfloat16* __restrict__ attno) {
  __shared__ __hip_bfloat16 ldsK[2][2][32 * 256];  // [group][buf][kv 32][d 256]  64 KB
  __shared__ __hip_bfloat16 ldsV[2][2][256 * 32];  // [group][buf][d 256][kv 32]  64 KB
  __shared__ float mlx[8][2][32];                  // [wave][m,l][q]              2 KB
  const int tid = threadIdx.x, w = tid >> 6, l = tid & 63;
  const int l31 = l & 31, hi = l >> 5;
  const int g = w >> 2, gt = tid & 255;
  const int bid = blockIdx.x;
  const int bh = (bid & 7) * 2 + ((bid >> 3) & 1);  // XCD-affine: 2 bh per XCD
  const int qt = bid >> 4;
  const int b = bh >> 2, h = bh & 3;
  const int qsub = qt * 128 + (w & 3) * 32;
  const int kvbase = g * 1024;
  // Q B-frags: bq[kst] = Q[q=l31][kst*16 + hi*8 + j]
  bf16x8 bq[16];
  {
    const __hip_bfloat16* Qp = qkv + (size_t)(b * SEQ + qsub + l31) * 3072 + h * HD + hi * 8;
#pragma unroll
    for (int kst = 0; kst < 16; kst++) bq[kst] = ldg8(Qp + kst * 16);
  }
  // K staging: round i (i<4) writes rows kv=i*8+(gt>>5); phys chunk gt&31 holds data ^(kv&7)
  const int kcd = (gt & 31) ^ ((gt >> 5) & 7);
  const __hip_bfloat16* Kg =
      qkv + (size_t)(b * SEQ + kvbase + (gt >> 5)) * 3072 + 1024 + h * HD + kcd * 8;
  // V staging: round i (i<4) writes rows d=i*64+(gt>>2); phys chunk gt&3 holds data ^((d>>1)&3)
  const int vcd = (gt & 3) ^ ((gt >> 3) & 3);
  const __hip_bfloat16* Vg =
      vt + (size_t)bh * HD * SEQ + (size_t)(gt >> 2) * SEQ + kvbase + vcd * 8;
  __hip_bfloat16* lKb[2] = {&ldsK[g][0][0], &ldsK[g][1][0]};
  __hip_bfloat16* lVb[2] = {&ldsV[g][0][0], &ldsV[g][1][0]};

  f32x16 oacc[8] = {};
  float m_run = -1e30f, lsum = 0.f;

  // prologue: stage tile 0 into buf 0
#pragma unroll
  for (int i = 0; i < 4; i++) gload16(Kg + (size_t)(i * 8) * 3072, lKb[0] + i * 2048 + gt * 8);
#pragma unroll
  for (int i = 0; i < 4; i++) gload16(Vg + (size_t)(i * 64) * SEQ, lVb[0] + i * 2048 + gt * 8);
  __syncthreads();

#pragma unroll 2
  for (int t = 0; t < 32; ++t) {
    const int cur = t & 1;
    // ---- issue next tile's loads first: latency hides under this tile's compute ----
    if (t + 1 < 32) {
      const int nk = (t + 1) * 32;
#pragma unroll
      for (int i = 0; i < 4; i++)
        gload16(Kg + (size_t)(nk + i * 8) * 3072, lKb[cur ^ 1] + i * 2048 + gt * 8);
#pragma unroll
      for (int i = 0; i < 4; i++)
        gload16(Vg + (size_t)(i * 64) * SEQ + nk, lVb[cur ^ 1] + i * 2048 + gt * 8);
    }
    const __hip_bfloat16* lK = lKb[cur];
    const __hip_bfloat16* lV = lVb[cur];
    // ---- S^T[kv32][q]: 16 MFMAs, 2 independent chains ----
    f32x16 sa = {}, sb = {};
    const int ksw = l31 & 7;
    __builtin_amdgcn_s_setprio(1);
#pragma unroll
    for (int kst = 0; kst < 8; kst++) {
      bf16x8 aka = ldg8(&lK[l31 * 256 + (((4 * kst + hi) ^ ksw) << 3)]);
      bf16x8 akb = ldg8(&lK[l31 * 256 + (((4 * kst + 2 + hi) ^ ksw) << 3)]);
      sa = __builtin_amdgcn_mfma_f32_32x32x16_bf16(aka, bq[2 * kst], sa, 0, 0, 0);
      sb = __builtin_amdgcn_mfma_f32_32x32x16_bf16(akb, bq[2 * kst + 1], sb, 0, 0, 0);
    }
    __builtin_amdgcn_s_setprio(0);
#pragma unroll
    for (int r = 0; r < 16; r++) sa[r] = (sa[r] + sb[r]) * 0.0625f;  // hd^-0.5
    // ---- in-register online softmax (lane owns q=l31; partner l^32 has other 16 rows) ----
    float rmax = sa[0];
#pragma unroll
    for (int r = 1; r < 16; r++) rmax = fmaxf(rmax, sa[r]);
    rmax = fmaxf(rmax, __shfl_xor(rmax, 32));
    if (rmax > m_run + 8.f) {  // defer-max THR=8
      const float alpha = __expf(m_run - rmax);
      m_run = rmax;
      lsum *= alpha;
#pragma unroll
      for (int dt = 0; dt < 8; dt++)
#pragma unroll
        for (int r = 0; r < 16; r++) oacc[dt][r] *= alpha;
    }
    float psum = 0.f;
#pragma unroll
    for (int r = 0; r < 16; r++) {
      sa[r] = __expf(sa[r] - m_run);  // bounded by e^8
      psum += sa[r];
    }
    lsum += psum + __shfl_xor(psum, 32);
    // ---- pack P^T into B-frags + PV (2 k-steps of 16 kv) ----
#pragma unroll
    for (int ks = 0; ks < 2; ks++) {
      const int rb = ks * 8;
      // own packs: a* = kv16 (4hi+0..3); b* = kv16 (8+4hi..11+4hi)
      unsigned a0 = pack2(sa[rb + 0], sa[rb + 1]);
      unsigned a1 = pack2(sa[rb + 2], sa[rb + 3]);
      unsigned b0 = pack2(sa[rb + 4], sa[rb + 5]);
      unsigned b1 = pack2(sa[rb + 6], sa[rb + 7]);
      // hi=0 sends b*, receives partner a* (kv16 4-7); hi=1 sends a*, receives b* (kv16 8-11)
      unsigned s0 = (unsigned)__shfl_xor((int)(hi ? a0 : b0), 32);
      unsigned s1 = (unsigned)__shfl_xor((int)(hi ? a1 : b1), 32);
      union { unsigned u[4]; bf16x8 v; } pw;
      pw.u[0] = hi ? s0 : a0;  // k = hi*8 + {0,1}
      pw.u[1] = hi ? s1 : a1;  // k = hi*8 + {2,3}
      pw.u[2] = hi ? b0 : s0;  // k = hi*8 + {4,5}
      pw.u[3] = hi ? b1 : s1;  // k = hi*8 + {6,7}
      // PV: O^T[d][q] += V^T[d][kv] * P^T[kv][q]; A-frag k=hi*8+j -> data chunk ks*2+hi
      __builtin_amdgcn_s_setprio(1);
#pragma unroll
      for (int dt = 0; dt < 8; dt++) {
        const int drow = dt * 32 + l31;
        bf16x8 av = ldg8(&lV[drow * 32 + (((ks * 2 + hi) ^ ((drow >> 1) & 3)) << 3)]);
        oacc[dt] = __builtin_amdgcn_mfma_f32_32x32x16_bf16(av, pw.v, oacc[dt], 0, 0, 0);
      }
      __builtin_amdgcn_s_setprio(0);
    }
    // one barrier per iter: drains in-flight next-tile loads AND guards buffer reuse
    __syncthreads();
  }
  // ---- cross-group flash-combine (through dead K/V LDS; no global partials) ----
  if (l < 32) {
    mlx[w][0][l] = m_run;
    mlx[w][1][l] = lsum;
  }
  __syncthreads();
  {
    const float m_o = mlx[w ^ 4][0][l31];
    const float l_o = mlx[w ^ 4][1][l31];
    const float mm = fmaxf(m_run, m_o);
    const float e_s = __expf(m_run - mm), e_o = __expf(m_o - mm);
    const float wgt = e_s / (e_s * lsum + e_o * l_o);
#pragma unroll
    for (int dt = 0; dt < 8; dt++)
#pragma unroll
      for (int r = 0; r < 16; r++) oacc[dt][r] *= wgt;
  }
  const int pair = w & 3;
  float* xch = pair < 2 ? reinterpret_cast<float*>(&ldsK[0][0][0]) + pair * 8192
                        : reinterpret_cast<float*>(&ldsV[0][0][0]) + (pair - 2) * 8192;
  // exchange layout: float[32 q][256 d], 16B d-chunk swizzled ^ (q&7)
  if (g == 0) {
#pragma unroll
    for (int dt = 0; dt < 8; dt++)
#pragma unroll
      for (int rq = 0; rq < 4; rq++) {
        const int dch = dt * 8 + 2 * rq + hi;
        f32x4 v;
#pragma unroll
        for (int i = 0; i < 4; i++) v[i] = oacc[dt][4 * rq + i];
        *reinterpret_cast<f32x4*>(&xch[l31 * 256 + ((dch ^ (l31 & 7)) << 2)]) = v;
      }
  }
  __syncthreads();
  if (g == 1) {
    const size_t rowb = (size_t)(b * SEQ + qsub + l31) * DM + h * HD;
#pragma unroll
    for (int dt = 0; dt < 8; dt++)
#pragma unroll
      for (int rq = 0; rq < 4; rq++) {
        const int dch = dt * 8 + 2 * rq + hi;
        f32x4 p = *reinterpret_cast<const f32x4*>(&xch[l31 * 256 + ((dch ^ (l31 & 7)) << 2)]);
        short4 sv;
        sv.x = bfbits(p[0] + oacc[dt][4 * rq + 0]);
        sv.y = bfbits(p[1] + oacc[dt][4 * rq + 1]);
        sv.z = bfbits(p[2] + oacc[dt][4 * rq + 2]);
        sv.w = bfbits(p[3] + oacc[dt][4 * rq + 3]);
        *reinterpret_cast<short4*>(
            reinterpret_cast<short*>(attno + rowb + dt * 32 + 8 * rq + 4 * hi)) = sv;
      }
  }
}

// ---------------- LayerNorm: 1 wave per 1024-row, BF16 input, ORIGINAL lane mapping ------
// Round-11 post-mortem: changing the lane map to contiguous-16/lane broke gamma/beta/out
// coalescing (stride-64B lanes). v3 keeps the 10x-passed interleaved map (chunk i*64+l) for
// ALL streams; only the y-load narrows to short4 (8B/lane, consecutive lanes -> consecutive
// 8B chunks = coalesced 512B/instr). f32 math; f32 output.
__global__ __launch_bounds__(256) void layernorm_k(const __hip_bfloat16* __restrict__ y,
                                                   const float* __restrict__ gamma,
                                                   const float* __restrict__ beta,
                                                   float* __restrict__ out) {
  const int w = threadIdx.x >> 6, l = threadIdx.x & 63;
  const size_t row = (size_t)blockIdx.x * 4 + w;
  const short4* yp = reinterpret_cast<const short4*>(y + row * DM);  // 256 chunks of 4 bf16
  float f[4][4];
  float s = 0.f, s2 = 0.f;
#pragma unroll
  for (int i = 0; i < 4; i++) {
    short4 v = yp[i * 64 + l];
    f[i][0] = b2f(v.x);
    f[i][1] = b2f(v.y);
    f[i][2] = b2f(v.z);
    f[i][3] = b2f(v.w);
#pragma unroll
    for (int j = 0; j < 4; j++) {
      s += f[i][j];
      s2 += f[i][j] * f[i][j];
    }
  }
#pragma unroll
  for (int off = 1; off < 64; off <<= 1) {
    s += __shfl_xor(s, off);
    s2 += __shfl_xor(s2, off);
  }
  const float mu = s * (1.f / 1024.f);
  const float rs = rsqrtf(s2 * (1.f / 1024.f) - mu * mu + 1e-5f);
  const float4* gp = reinterpret_cast<const float4*>(gamma);
  const float4* bp = reinterpret_cast<const float4*>(beta);
  float4* op = reinterpret_cast<float4*>(out + row * DM);
#pragma unroll
  for (int i = 0; i < 4; i++) {
    float4 g = gp[i * 64 + l], bb = bp[i * 64 + l];
    float4 o;
    o.x = (f[i][0] - mu) * rs * g.x + bb.x;
    o.y = (f[i][1] - mu) * rs * g.y + bb.y;
    o.z = (f[i][2] - mu) * rs * g.z + bb.z;
    o.w = (f[i][3] - mu) * rs * g.w + bb.w;
    op[i * 64 + l] = o;
  }
}

extern "C" void kernel_launch(void* const* d_in, const int* in_sizes, int n_in,
                              void* d_out, int out_size, void* d_ws, size_t ws_size,
                              hipStream_t stream) {
  const float* x     = (const float*)d_in[0];
  const float* qkv_w = (const float*)d_in[1];
  const float* qkv_b = (const float*)d_in[2];
  const float* wo_w  = (const float*)d_in[3];
  const float* wo_b  = (const float*)d_in[4];
  const float* gamma = (const float*)d_in[5];
  const float* beta  = (const float*)d_in[6];
  float* out = (float*)d_out;
  char* ws = (char*)d_ws;
  // v0 workspace layout (passed 11x): strictly sequential lifetimes, no overlap while live.
  __hip_bfloat16* xbf   = (__hip_bfloat16*)(ws);             // dead after gemm<0>
  __hip_bfloat16* qkvwb = (__hip_bfloat16*)(ws + 16777216);  // dead after gemm<0>
  __hip_bfloat16* wowb  = (__hip_bfloat16*)(ws + 23068672);  // live until gemm<1>
  __hip_bfloat16* qkv   = (__hip_bfloat16*)(ws + 25165824);  // dead after flash
  __hip_bfloat16* ybb   = (__hip_bfloat16*)(ws + 25165824);  // gemm<1> out bf16 (aliases dead qkv)
  __hip_bfloat16* vt    = (__hip_bfloat16*)(ws + 75497472);  // dead after flash
  __hip_bfloat16* attno = xbf;                               // flash out (aliases dead xbf)

  cvt3<<<12288, 256, 0, stream>>>(x, qkv_w, wo_w, xbf, qkvwb, wowb);
  gemm_bt<0><<<dim3(24, 64), 256, 0, stream>>>(xbf, qkvwb, qkv_b, nullptr, qkv,
                                               vt, 8192, 3072, 1024);
  flash_attn<<<256, 512, 0, stream>>>(qkv, vt, attno);
  gemm_bt<1><<<dim3(8, 64), 256, 0, stream>>>(attno, wowb, wo_b, x, ybb,
                                              nullptr, 8192, 1024, 1024);
  layernorm_k<<<2048, 256, 0, stream>>>(ybb, gamma, beta, out);
}

// Round 14
// 225.125 us; speedup vs baseline: 1.1475x; 1.0098x over previous
//
#include <hip/hip_runtime.h>
#include <hip/hip_bf16.h>

#define SEQ 2048
#define DM  1024
#define NH  4
#define HD  256

typedef __attribute__((ext_vector_type(4))) float f32x4;
typedef __attribute__((ext_vector_type(16))) float f32x16;
typedef __attribute__((ext_vector_type(8))) short bf16x8;

__device__ __forceinline__ void gload16(const void* g, void* l) {
  __builtin_amdgcn_global_load_lds(
      (__attribute__((address_space(1))) void*)(unsigned long long)(g),
      (__attribute__((address_space(3))) void*)(l), 16, 0, 0);
}

__device__ __forceinline__ bf16x8 ldg8(const __hip_bfloat16* p) {
  return *reinterpret_cast<const bf16x8*>(p);
}

__device__ __forceinline__ unsigned pack2(float a, float b) {
  __hip_bfloat162 t = __float22bfloat162_rn(make_float2(a, b));
  return *reinterpret_cast<unsigned*>(&t);  // short0=a, short1=b
}

__device__ __forceinline__ short bfbits(float x) {
  __hip_bfloat16 h = __float2bfloat16(x);
  return *reinterpret_cast<short*>(&h);
}

__device__ __forceinline__ float b2f(short s) {
  union { unsigned u; float f; } c;
  c.u = ((unsigned)(unsigned short)s) << 16;
  return c.f;
}

// base-2 exp via the HW instruction (v_exp_f32: D = 2^S0, cdna4_isa.md §3).
// (round-13 lesson: __exp2f collides with glibc math.h macros — use asm.)
__device__ __forceinline__ float ex2(float x) {
  float r;
  asm volatile("v_exp_f32 %0, %1" : "=v"(r) : "v"(x));
  return r;
}

// ---------------- fp32 -> bf16 (x, qkv_w, wo_w fused: 3 launches -> 1) ----------------
__global__ __launch_bounds__(256) void cvt3(const float* __restrict__ x,
                                            const float* __restrict__ qw,
                                            const float* __restrict__ ww,
                                            __hip_bfloat16* __restrict__ xo,
                                            __hip_bfloat16* __restrict__ qo,
                                            __hip_bfloat16* __restrict__ wo) {
  int i = blockIdx.x * 256 + threadIdx.x;  // grid covers exactly 3145728 float4s
  const float* src;
  __hip_bfloat16* dst;
  int j;
  if (i < 2097152) {
    src = x; dst = xo; j = i;
  } else if (i < 2883584) {
    src = qw; dst = qo; j = i - 2097152;
  } else {
    src = ww; dst = wo; j = i - 2883584;
  }
  float4 v = reinterpret_cast<const float4*>(src)[j];
  __hip_bfloat162* o2 = reinterpret_cast<__hip_bfloat162*>(dst);
  o2[j * 2 + 0] = __float22bfloat162_rn(make_float2(v.x, v.y));
  o2[j * 2 + 1] = __float22bfloat162_rn(make_float2(v.z, v.w));
}

// ---------------- GEMM: C[m,n] = sum_k A[m,k]*B[n,k] (+bias, +resid) ----------------
// v4 (rounds 8-12, passed): counted-vmcnt 3-buffer ring + V-transpose fused epilogue;
// EPI=1 writes y in BF16. FROZEN.
template <int EPI>
__global__ __launch_bounds__(256, 3) void gemm_bt(
    const __hip_bfloat16* __restrict__ A, const __hip_bfloat16* __restrict__ Bw,
    const float* __restrict__ bias, const float* __restrict__ resid,
    __hip_bfloat16* __restrict__ Cb,
    __hip_bfloat16* __restrict__ vtr, int M, int N, int K) {
  __shared__ __hip_bfloat16 lA[3][128 * 32];  // 3 x 8 KB
  __shared__ __hip_bfloat16 lB[3][128 * 32];  // 3 x 8 KB   (48 KB -> 3 blocks/CU)
  const int t = threadIdx.x;
  const int w = t >> 6, l = t & 63;
  const int lg = l >> 4, li = l & 15;
  const int m0 = blockIdx.y * 128, n0 = blockIdx.x * 128;
  const int wm = (w >> 1) * 64, wn = (w & 1) * 64;
  // staging: thread covers rows (t>>2) and 64+(t>>2); pre-swizzled data chunk (same both rows)
  const int ca = (((t & 3) ^ ((t >> 3) & 3))) * 8;
  const __hip_bfloat16* gA0 = A + (size_t)(m0 + (t >> 2)) * K + ca;
  const __hip_bfloat16* gA1 = A + (size_t)(m0 + 64 + (t >> 2)) * K + ca;
  const __hip_bfloat16* gB0 = Bw + (size_t)(n0 + (t >> 2)) * K + ca;
  const __hip_bfloat16* gB1 = Bw + (size_t)(n0 + 64 + (t >> 2)) * K + ca;
  const int loff = t * 8;  // LDS linear dest (wave-uniform base + lane*16B)

  auto STAGE = [&](int kt, int buf) {
    const int k0 = kt * 32;
    gload16(gA0 + k0, &lA[buf][loff]);
    gload16(gA1 + k0, &lA[buf][loff + 2048]);
    gload16(gB0 + k0, &lB[buf][loff]);
    gload16(gB1 + k0, &lB[buf][loff + 2048]);
  };

  f32x4 acc[4][4] = {};
  const int T = K >> 5;
  STAGE(0, 0);
  STAGE(1, 1);
  asm volatile("s_waitcnt vmcnt(4)" ::: "memory");
  __builtin_amdgcn_sched_barrier(0);
  __builtin_amdgcn_s_barrier();
  __builtin_amdgcn_sched_barrier(0);
  int cur = 0, nx2 = 2;
  for (int kt = 0; kt < T; ++kt) {
    if (kt + 2 < T) STAGE(kt + 2, nx2);
    bf16x8 af[4], bfr[4];
#pragma unroll
    for (int i = 0; i < 4; i++) {
      const int row = wm + i * 16 + li;
      af[i] = ldg8(&lA[cur][row * 32 + ((lg ^ ((row >> 1) & 3)) << 3)]);
    }
#pragma unroll
    for (int i = 0; i < 4; i++) {
      const int row = wn + i * 16 + li;
      bfr[i] = ldg8(&lB[cur][row * 32 + ((lg ^ ((row >> 1) & 3)) << 3)]);
    }
    asm volatile("s_waitcnt lgkmcnt(0)" ::: "memory");
    __builtin_amdgcn_sched_barrier(0);
#pragma unroll
    for (int mi = 0; mi < 4; mi++)
#pragma unroll
      for (int ni = 0; ni < 4; ni++)
        acc[mi][ni] = __builtin_amdgcn_mfma_f32_16x16x32_bf16(af[mi], bfr[ni], acc[mi][ni], 0, 0, 0);
    if (kt + 2 < T) {
      asm volatile("s_waitcnt vmcnt(4)" ::: "memory");
    } else {
      asm volatile("s_waitcnt vmcnt(0)" ::: "memory");
    }
    __builtin_amdgcn_sched_barrier(0);
    __builtin_amdgcn_s_barrier();
    __builtin_amdgcn_sched_barrier(0);
    cur = (cur == 2) ? 0 : cur + 1;
    nx2 = (nx2 == 2) ? 0 : nx2 + 1;
  }
#pragma unroll
  for (int ni = 0; ni < 4; ni++) {
    const int col = n0 + wn + ni * 16 + li;
    const float bv = bias[col];
    if (EPI == 0 && col >= 2048) {
      // V projection -> vt[(b*4+h)*256+d][s], fused transpose
      const int hh = (col - 2048) >> 8;   // uniform per ni
      const int dd = (col - 2048) & 255;  // per-lane
      __hip_bfloat16* vcol =
          vtr + ((size_t)((m0 >> 11) * 4 + hh) * 256 + dd) * 2048 + (m0 & 2047);
#pragma unroll
      for (int mi = 0; mi < 4; mi++) {
        const int off = wm + mi * 16 + lg * 4;
#pragma unroll
        for (int r = 0; r < 4; r++)
          vcol[off + r] = __float2bfloat16(acc[mi][ni][r] + bv);
      }
    } else {
#pragma unroll
      for (int mi = 0; mi < 4; mi++) {
        const int rowb = m0 + wm + mi * 16 + lg * 4;
#pragma unroll
        for (int r = 0; r < 4; r++) {
          const size_t idx = (size_t)(rowb + r) * N + col;
          float v = acc[mi][ni][r] + bv;
          if (EPI) {
            Cb[idx] = __float2bfloat16(v + resid[idx]);  // y in bf16
          } else {
            Cb[idx] = __float2bfloat16(v);
          }
        }
      }
    }
  }
}

// ---------------- flash attention v11: v9 core + exp2-domain softmax + max3 reduce --------
// Structure/layout/staging BYTE-IDENTICAL to v9 (5x passed, 117.5us). Exact-math micro-opts:
//  * exp2 domain: scale const folds log2(e) (0.0625*1.4426950 = 0.09016844); m_run tracked in
//    log2 units; ex2() = single v_exp_f32 (HW IS base-2) vs __expf's mul+exp. THR = 8*log2e.
//    Identity 2^(s*log2e - m*log2e) = e^(s-m): same values up to rounding.
//  * max3-shaped reduce: nested fmax triples -> v_max3_f32 (~8 ops vs 15).
__global__ __launch_bounds__(512, 2) void flash_attn(const __hip_bfloat16* __restrict__ qkv,
                                                     const __hip_bfloat16* __restrict__ vt,
                                                     __hip_bfloat16* __restrict__ attno) {
  __shared__ __hip_bfloat16 ldsK[2][2][32 * 256];  // [group][buf][kv 32][d 256]  64 KB
  __shared__ __hip_bfloat16 ldsV[2][2][256 * 32];  // [group][buf][d 256][kv 32]  64 KB
  __shared__ float mlx[8][2][32];                  // [wave][m,l][q]              2 KB
  const int tid = threadIdx.x, w = tid >> 6, l = tid & 63;
  const int l31 = l & 31, hi = l >> 5;
  const int g = w >> 2, gt = tid & 255;
  const int bid = blockIdx.x;
  const int bh = (bid & 7) * 2 + ((bid >> 3) & 1);  // XCD-affine: 2 bh per XCD
  const int qt = bid >> 4;
  const int b = bh >> 2, h = bh & 3;
  const int qsub = qt * 128 + (w & 3) * 32;
  const int kvbase = g * 1024;
  // Q B-frags: bq[kst] = Q[q=l31][kst*16 + hi*8 + j]
  bf16x8 bq[16];
  {
    const __hip_bfloat16* Qp = qkv + (size_t)(b * SEQ + qsub + l31) * 3072 + h * HD + hi * 8;
#pragma unroll
    for (int kst = 0; kst < 16; kst++) bq[kst] = ldg8(Qp + kst * 16);
  }
  // K staging: round i (i<4) writes rows kv=i*8+(gt>>5); phys chunk gt&31 holds data ^(kv&7)
  const int kcd = (gt & 31) ^ ((gt >> 5) & 7);
  const __hip_bfloat16* Kg =
      qkv + (size_t)(b * SEQ + kvbase + (gt >> 5)) * 3072 + 1024 + h * HD + kcd * 8;
  // V staging: round i (i<4) writes rows d=i*64+(gt>>2); phys chunk gt&3 holds data ^((d>>1)&3)
  const int vcd = (gt & 3) ^ ((gt >> 3) & 3);
  const __hip_bfloat16* Vg =
      vt + (size_t)bh * HD * SEQ + (size_t)(gt >> 2) * SEQ + kvbase + vcd * 8;
  __hip_bfloat16* lKb[2] = {&ldsK[g][0][0], &ldsK[g][1][0]};
  __hip_bfloat16* lVb[2] = {&ldsV[g][0][0], &ldsV[g][1][0]};

  f32x16 oacc[8] = {};
  float m_run = -1e30f, lsum = 0.f;

  // prologue: stage tile 0 into buf 0
#pragma unroll
  for (int i = 0; i < 4; i++) gload16(Kg + (size_t)(i * 8) * 3072, lKb[0] + i * 2048 + gt * 8);
#pragma unroll
  for (int i = 0; i < 4; i++) gload16(Vg + (size_t)(i * 64) * SEQ, lVb[0] + i * 2048 + gt * 8);
  __syncthreads();

#pragma unroll 2
  for (int t = 0; t < 32; ++t) {
    const int cur = t & 1;
    // ---- issue next tile's loads first: latency hides under this tile's compute ----
    if (t + 1 < 32) {
      const int nk = (t + 1) * 32;
#pragma unroll
      for (int i = 0; i < 4; i++)
        gload16(Kg + (size_t)(nk + i * 8) * 3072, lKb[cur ^ 1] + i * 2048 + gt * 8);
#pragma unroll
      for (int i = 0; i < 4; i++)
        gload16(Vg + (size_t)(i * 64) * SEQ + nk, lVb[cur ^ 1] + i * 2048 + gt * 8);
    }
    const __hip_bfloat16* lK = lKb[cur];
    const __hip_bfloat16* lV = lVb[cur];
    // ---- S^T[kv32][q]: 16 MFMAs, 2 independent chains ----
    f32x16 sa = {}, sb = {};
    const int ksw = l31 & 7;
    __builtin_amdgcn_s_setprio(1);
#pragma unroll
    for (int kst = 0; kst < 8; kst++) {
      bf16x8 aka = ldg8(&lK[l31 * 256 + (((4 * kst + hi) ^ ksw) << 3)]);
      bf16x8 akb = ldg8(&lK[l31 * 256 + (((4 * kst + 2 + hi) ^ ksw) << 3)]);
      sa = __builtin_amdgcn_mfma_f32_32x32x16_bf16(aka, bq[2 * kst], sa, 0, 0, 0);
      sb = __builtin_amdgcn_mfma_f32_32x32x16_bf16(akb, bq[2 * kst + 1], sb, 0, 0, 0);
    }
    __builtin_amdgcn_s_setprio(0);
#pragma unroll
    for (int r = 0; r < 16; r++) sa[r] = (sa[r] + sb[r]) * 0.09016844f;  // hd^-0.5 * log2(e)
    // ---- in-register online softmax, exp2 domain (lane owns q=l31; partner l^32 rest) ----
    float m0 = fmaxf(fmaxf(sa[0], sa[1]), sa[2]);
    float m1 = fmaxf(fmaxf(sa[3], sa[4]), sa[5]);
    float m2 = fmaxf(fmaxf(sa[6], sa[7]), sa[8]);
    float m3 = fmaxf(fmaxf(sa[9], sa[10]), sa[11]);
    float m4 = fmaxf(fmaxf(sa[12], sa[13]), sa[14]);
    float rmax = fmaxf(fmaxf(fmaxf(m0, m1), m2), fmaxf(fmaxf(m3, m4), sa[15]));
    rmax = fmaxf(rmax, __shfl_xor(rmax, 32));
    if (rmax > m_run + 11.5415603f) {  // defer-max THR=8 (log2 units)
      const float alpha = ex2(m_run - rmax);
      m_run = rmax;
      lsum *= alpha;
#pragma unroll
      for (int dt = 0; dt < 8; dt++)
#pragma unroll
        for (int r = 0; r < 16; r++) oacc[dt][r] *= alpha;
    }
    float psum = 0.f;
#pragma unroll
    for (int r = 0; r < 16; r++) {
      sa[r] = ex2(sa[r] - m_run);  // bounded by e^8
      psum += sa[r];
    }
    lsum += psum + __shfl_xor(psum, 32);
    // ---- pack P^T into B-frags + PV (2 k-steps of 16 kv) ----
#pragma unroll
    for (int ks = 0; ks < 2; ks++) {
      const int rb = ks * 8;
      // own packs: a* = kv16 (4hi+0..3); b* = kv16 (8+4hi..11+4hi)
      unsigned a0 = pack2(sa[rb + 0], sa[rb + 1]);
      unsigned a1 = pack2(sa[rb + 2], sa[rb + 3]);
      unsigned b0 = pack2(sa[rb + 4], sa[rb + 5]);
      unsigned b1 = pack2(sa[rb + 6], sa[rb + 7]);
      // hi=0 sends b*, receives partner a* (kv16 4-7); hi=1 sends a*, receives b* (kv16 8-11)
      unsigned s0 = (unsigned)__shfl_xor((int)(hi ? a0 : b0), 32);
      unsigned s1 = (unsigned)__shfl_xor((int)(hi ? a1 : b1), 32);
      union { unsigned u[4]; bf16x8 v; } pw;
      pw.u[0] = hi ? s0 : a0;  // k = hi*8 + {0,1}
      pw.u[1] = hi ? s1 : a1;  // k = hi*8 + {2,3}
      pw.u[2] = hi ? b0 : s0;  // k = hi*8 + {4,5}
      pw.u[3] = hi ? b1 : s1;  // k = hi*8 + {6,7}
      // PV: O^T[d][q] += V^T[d][kv] * P^T[kv][q]; A-frag k=hi*8+j -> data chunk ks*2+hi
      __builtin_amdgcn_s_setprio(1);
#pragma unroll
      for (int dt = 0; dt < 8; dt++) {
        const int drow = dt * 32 + l31;
        bf16x8 av = ldg8(&lV[drow * 32 + (((ks * 2 + hi) ^ ((drow >> 1) & 3)) << 3)]);
        oacc[dt] = __builtin_amdgcn_mfma_f32_32x32x16_bf16(av, pw.v, oacc[dt], 0, 0, 0);
      }
      __builtin_amdgcn_s_setprio(0);
    }
    // one barrier per iter: drains in-flight next-tile loads AND guards buffer reuse
    __syncthreads();
  }
  // ---- cross-group flash-combine, exp2 domain (through dead K/V LDS) ----
  if (l < 32) {
    mlx[w][0][l] = m_run;
    mlx[w][1][l] = lsum;
  }
  __syncthreads();
  {
    const float m_o = mlx[w ^ 4][0][l31];
    const float l_o = mlx[w ^ 4][1][l31];
    const float mm = fmaxf(m_run, m_o);
    const float e_s = ex2(m_run - mm), e_o = ex2(m_o - mm);
    const float wgt = e_s / (e_s * lsum + e_o * l_o);
#pragma unroll
    for (int dt = 0; dt < 8; dt++)
#pragma unroll
      for (int r = 0; r < 16; r++) oacc[dt][r] *= wgt;
  }
  const int pair = w & 3;
  float* xch = pair < 2 ? reinterpret_cast<float*>(&ldsK[0][0][0]) + pair * 8192
                        : reinterpret_cast<float*>(&ldsV[0][0][0]) + (pair - 2) * 8192;
  // exchange layout: float[32 q][256 d], 16B d-chunk swizzled ^ (q&7)
  if (g == 0) {
#pragma unroll
    for (int dt = 0; dt < 8; dt++)
#pragma unroll
      for (int rq = 0; rq < 4; rq++) {
        const int dch = dt * 8 + 2 * rq + hi;
        f32x4 v;
#pragma unroll
        for (int i = 0; i < 4; i++) v[i] = oacc[dt][4 * rq + i];
        *reinterpret_cast<f32x4*>(&xch[l31 * 256 + ((dch ^ (l31 & 7)) << 2)]) = v;
      }
  }
  __syncthreads();
  if (g == 1) {
    const size_t rowb = (size_t)(b * SEQ + qsub + l31) * DM + h * HD;
#pragma unroll
    for (int dt = 0; dt < 8; dt++)
#pragma unroll
      for (int rq = 0; rq < 4; rq++) {
        const int dch = dt * 8 + 2 * rq + hi;
        f32x4 p = *reinterpret_cast<const f32x4*>(&xch[l31 * 256 + ((dch ^ (l31 & 7)) << 2)]);
        short4 sv;
        sv.x = bfbits(p[0] + oacc[dt][4 * rq + 0]);
        sv.y = bfbits(p[1] + oacc[dt][4 * rq + 1]);
        sv.z = bfbits(p[2] + oacc[dt][4 * rq + 2]);
        sv.w = bfbits(p[3] + oacc[dt][4 * rq + 3]);
        *reinterpret_cast<short4*>(
            reinterpret_cast<short*>(attno + rowb + dt * 32 + 8 * rq + 4 * hi)) = sv;
      }
  }
}

// ---------------- LayerNorm: 1 wave per 1024-row, BF16 input (round-12, passed) ----------
__global__ __launch_bounds__(256) void layernorm_k(const __hip_bfloat16* __restrict__ y,
                                                   const float* __restrict__ gamma,
                                                   const float* __restrict__ beta,
                                                   float* __restrict__ out) {
  const int w = threadIdx.x >> 6, l = threadIdx.x & 63;
  const size_t row = (size_t)blockIdx.x * 4 + w;
  const short4* yp = reinterpret_cast<const short4*>(y + row * DM);  // 256 chunks of 4 bf16
  float f[4][4];
  float s = 0.f, s2 = 0.f;
#pragma unroll
  for (int i = 0; i < 4; i++) {
    short4 v = yp[i * 64 + l];
    f[i][0] = b2f(v.x);
    f[i][1] = b2f(v.y);
    f[i][2] = b2f(v.z);
    f[i][3] = b2f(v.w);
#pragma unroll
    for (int j = 0; j < 4; j++) {
      s += f[i][j];
      s2 += f[i][j] * f[i][j];
    }
  }
#pragma unroll
  for (int off = 1; off < 64; off <<= 1) {
    s += __shfl_xor(s, off);
    s2 += __shfl_xor(s2, off);
  }
  const float mu = s * (1.f / 1024.f);
  const float rs = rsqrtf(s2 * (1.f / 1024.f) - mu * mu + 1e-5f);
  const float4* gp = reinterpret_cast<const float4*>(gamma);
  const float4* bp = reinterpret_cast<const float4*>(beta);
  float4* op = reinterpret_cast<float4*>(out + row * DM);
#pragma unroll
  for (int i = 0; i < 4; i++) {
    float4 g = gp[i * 64 + l], bb = bp[i * 64 + l];
    float4 o;
    o.x = (f[i][0] - mu) * rs * g.x + bb.x;
    o.y = (f[i][1] - mu) * rs * g.y + bb.y;
    o.z = (f[i][2] - mu) * rs * g.z + bb.z;
    o.w = (f[i][3] - mu) * rs * g.w + bb.w;
    op[i * 64 + l] = o;
  }
}

extern "C" void kernel_launch(void* const* d_in, const int* in_sizes, int n_in,
                              void* d_out, int out_size, void* d_ws, size_t ws_size,
                              hipStream_t stream) {
  const float* x     = (const float*)d_in[0];
  const float* qkv_w = (const float*)d_in[1];
  const float* qkv_b = (const float*)d_in[2];
  const float* wo_w  = (const float*)d_in[3];
  const float* wo_b  = (const float*)d_in[4];
  const float* gamma = (const float*)d_in[5];
  const float* beta  = (const float*)d_in[6];
  float* out = (float*)d_out;
  char* ws = (char*)d_ws;
  // v0 workspace layout (passed 12x): strictly sequential lifetimes, no overlap while live.
  __hip_bfloat16* xbf   = (__hip_bfloat16*)(ws);             // dead after gemm<0>
  __hip_bfloat16* qkvwb = (__hip_bfloat16*)(ws + 16777216);  // dead after gemm<0>
  __hip_bfloat16* wowb  = (__hip_bfloat16*)(ws + 23068672);  // live until gemm<1>
  __hip_bfloat16* qkv   = (__hip_bfloat16*)(ws + 25165824);  // dead after flash
  __hip_bfloat16* ybb   = (__hip_bfloat16*)(ws + 25165824);  // gemm<1> out bf16 (aliases dead qkv)
  __hip_bfloat16* vt    = (__hip_bfloat16*)(ws + 75497472);  // dead after flash
  __hip_bfloat16* attno = xbf;                               // flash out (aliases dead xbf)

  cvt3<<<12288, 256, 0, stream>>>(x, qkv_w, wo_w, xbf, qkvwb, wowb);
  gemm_bt<0><<<dim3(24, 64), 256, 0, stream>>>(xbf, qkvwb, qkv_b, nullptr, qkv,
                                               vt, 8192, 3072, 1024);
  flash_attn<<<256, 512, 0, stream>>>(qkv, vt, attno);
  gemm_bt<1><<<dim3(8, 64), 256, 0, stream>>>(attno, wowb, wo_b, x, ybb,
                                              nullptr, 8192, 1024, 1024);
  layernorm_k<<<2048, 256, 0, stream>>>(ybb, gamma, beta, out);
}